// Round 8
// baseline (162.621 us; speedup 1.0000x reference)
//
#include <hip/hip_runtime.h>
#include <hip/hip_bf16.h>

#define BATCH 2
#define CH 256
#define NH 4
#define HD 64
#define NGROUP 8
#define CPG 32
#define NTOK 4096
#define EPSV 1e-5f
// scale = hd^-0.5 = 0.125, folded with log2(e) so P = exp2(q'.k)
#define QSCALE 0.1803368801111204f
#define NSPLIT 4

typedef __attribute__((ext_vector_type(8))) short short8;
typedef __attribute__((ext_vector_type(4))) short s4bf;
typedef __attribute__((ext_vector_type(4))) float float4v;

__device__ __forceinline__ unsigned short f2bf(float f) {
    union { float f; unsigned u; } v; v.f = f;
    unsigned r = v.u + 0x7FFF + ((v.u >> 16) & 1);
    return (unsigned short)(r >> 16);
}
__device__ __forceinline__ unsigned short f2bf_fast(float f) {
    union { float f; unsigned u; } v; v.f = f;
    return (unsigned short)((v.u + 0x8000u) >> 16);
}
__device__ __forceinline__ float bf2f(unsigned short u) {
    union { unsigned u; float f; } v; v.u = ((unsigned)u) << 16;
    return v.f;
}
// pack two f32 -> one VGPR holding two bf16
__device__ __forceinline__ unsigned pk2bf(float a, float b) {
#if __has_builtin(__builtin_amdgcn_cvt_pk_bf16_f32)
    typedef __attribute__((ext_vector_type(2))) __bf16 bf2v;
    bf2v p = __builtin_amdgcn_cvt_pk_bf16_f32(a, b);
    union { bf2v v; unsigned u; } c; c.v = p;
    return c.u;
#else
    return (unsigned)f2bf_fast(a) | ((unsigned)f2bf_fast(b) << 16);
#endif
}

// ---------------- prep: fused wcvt + gn_partial (independent work) ----------------
__global__ void prep(const float* __restrict__ x,
                     const float* __restrict__ qkv_w, const float* __restrict__ qkv_b,
                     const float* __restrict__ proj_w,
                     float* __restrict__ psum, float* __restrict__ psq,
                     unsigned short* __restrict__ wq, float* __restrict__ bq,
                     unsigned short* __restrict__ wp) {
    int bx = blockIdx.x;
    int t = threadIdx.x;
    if (bx < 256) {
        // -------- gn_partial --------
        int s = bx & 15, g = (bx >> 4) & 7, b = bx >> 7;
        const float* base = x + ((size_t)(b * CH + g * CPG)) * NTOK + (size_t)s * 8192;
        float sum = 0.f, sq = 0.f;
        const float4v* p4 = (const float4v*)base;
        for (int i = 0; i < 8; ++i) {
            float4v v = p4[t + i * 256];
            for (int j = 0; j < 4; ++j) { sum += v[j]; sq += v[j] * v[j]; }
        }
        for (int off = 32; off; off >>= 1) {
            sum += __shfl_down(sum, off, 64);
            sq  += __shfl_down(sq,  off, 64);
        }
        __shared__ float ls[8];
        int wave = t >> 6, lane = t & 63;
        if (lane == 0) { ls[wave * 2] = sum; ls[wave * 2 + 1] = sq; }
        __syncthreads();
        if (t == 0) {
            float S = 0.f, Q = 0.f;
            for (int w = 0; w < 4; ++w) { S += ls[w * 2]; Q += ls[w * 2 + 1]; }
            int idx = (b * NGROUP + g) * 16 + s;
            psum[idx] = S; psq[idx] = Q;
        }
    } else {
        // -------- wcvt --------
        int idx = (bx - 256) * 256 + t;
        int stride = 256 * 256;
        for (int i = idx; i < 3 * CH * CH; i += stride) {
            float f = qkv_w[i];
            if (i < CH * CH) f *= QSCALE;
            wq[i] = f2bf(f);
        }
        for (int i = idx; i < CH * CH; i += stride) wp[i] = f2bf(proj_w[i]);
        for (int i = idx; i < 3 * CH; i += stride) {
            float f = qkv_b[i];
            if (i < CH) f *= QSCALE;
            bq[i] = f;
        }
    }
}

// ---------------- GroupNorm: normalize + transpose (stats folded in) ----------------
__global__ void gn_norm(const float* __restrict__ x, const float* __restrict__ nw,
                        const float* __restrict__ nb_, const float* __restrict__ psum,
                        const float* __restrict__ psq, unsigned short* __restrict__ hT) {
    int t = threadIdx.x;
    int n = blockIdx.x * 64 + (t & 63);
    int g = blockIdx.y;                    // block covers exactly one group (32 ch)
    int cb = g * 32 + (t >> 6) * 8;
    int b = blockIdx.z;
    float S = 0.f, Q = 0.f;
    for (int s = 0; s < 16; ++s) {
        S += psum[(b * NGROUP + g) * 16 + s];
        Q += psq[(b * NGROUP + g) * 16 + s];
    }
    const float M = (float)(CPG * NTOK);
    float mean = S / M;
    float inv  = rsqrtf(Q / M - mean * mean + EPSV);
    short8 h8;
    for (int j = 0; j < 8; ++j) {
        int c = cb + j;
        float w  = nw[c] * inv;
        float bb = nb_[c] - mean * w;
        float v = x[((size_t)(b * CH + c)) * NTOK + n];
        h8[j] = (short)f2bf(v * w + bb);
    }
    *(short8*)(hT + ((size_t)b * NTOK + n) * CH + cb) = h8;
}

// ---------------- QKV GEMM: stage B once, 2 o-passes per block ----------------
__global__ __launch_bounds__(256) void qkv_gemm(const unsigned short* __restrict__ hT,
        const unsigned short* __restrict__ wq, const float* __restrict__ bq,
        unsigned short* __restrict__ qT, unsigned short* __restrict__ kT,
        unsigned short* __restrict__ vv) {
    int nb = blockIdx.x;       // 0..63 (n tile of 64)
    int og = blockIdx.y;       // 0..5  (o group of 128)
    int b  = blockIdx.z;
    int t = threadIdx.x;
    int wave = t >> 6, lane = t & 63;
    int l15 = lane & 15, quad = lane >> 4;

    __shared__ __align__(16) unsigned short bt[64 * 264];   // 132 dw stride (==4 mod 32)

    // stage B tile: 64 n-rows x 256 c
    for (int p = 0; p < 8; ++p) {
        int slot = p * 256 + t;
        int r = slot >> 5, c = slot & 31;
        *(short8*)(bt + r * 264 + c * 8) =
            *(const short8*)(hT + ((size_t)b * NTOK + nb * 64 + r) * CH + c * 8);
    }
    __syncthreads();

    for (int pass = 0; pass < 2; ++pass) {
        int o0 = og * 128 + pass * 64 + wave * 16;
        short8 aW[8];
        {
            const unsigned short* wr = wq + (size_t)(o0 + l15) * CH + quad * 8;
            for (int kc = 0; kc < 8; ++kc) aW[kc] = *(const short8*)(wr + kc * 32);
        }
        float4v acc[4];
        for (int nt = 0; nt < 4; ++nt) for (int r = 0; r < 4; ++r) acc[nt][r] = 0.f;
        for (int kc = 0; kc < 8; ++kc) {
            for (int nt = 0; nt < 4; ++nt) {
                short8 pb = *(const short8*)(bt + (nt * 16 + l15) * 264 + kc * 32 + quad * 8);
                acc[nt] = __builtin_amdgcn_mfma_f32_16x16x32_bf16(aW[kc], pb, acc[nt], 0, 0, 0);
            }
        }
        for (int nt = 0; nt < 4; ++nt) {
            int n = nb * 64 + nt * 16 + l15;
            for (int r = 0; r < 4; ++r) {
                int o = o0 + quad * 4 + r;
                float val = acc[nt][r] + bq[o];
                unsigned short bv = f2bf(val);
                int cch = o & 255;
                int seg = o >> 8;          // 0=q (pre-scaled), 1=k, 2=v
                int hh = cch >> 6, ci = cch & 63;
                if (seg == 0)      qT[(((size_t)b * NH + hh) * NTOK + n) * HD + ci] = bv;
                else if (seg == 1) kT[(((size_t)b * NH + hh) * NTOK + n) * HD + ci] = bv;
                else               vv[(((size_t)b * NH + hh) * HD + ci) * NTOK + n] = bv;
            }
        }
    }
}

// ---------------- Flash attention: 64-key tiles, 64 q/block, 8 blocks/CU ----------
// S^T = K*Q^T (A=K, B=Q): C-layout lane l15 = q-row, reg r = key quad*4+r ==
// A-fragment of mfma_16x16x16bf16_1k -> register P->PV, no LDS round-trip.
__global__ __launch_bounds__(256, 8) void attn_kernel(const unsigned short* __restrict__ qT,
        const unsigned short* __restrict__ kT, const unsigned short* __restrict__ vv,
        unsigned short* __restrict__ opb, float* __restrict__ lpb) {
    int nb = blockIdx.x;          // 0..63 : 64 query rows per block
    int h  = blockIdx.y;
    int zb = blockIdx.z;          // (b, split)
    int sp = zb & 3, b = zb >> 2;
    int t = threadIdx.x, wave = t >> 6, lane = t & 63;
    int l15 = lane & 15, quad = lane >> 4;
    int n0 = nb * 64 + wave * 16;      // wave owns 16 q-rows
    int kv0 = sp * (NTOK / NSPLIT);

    unsigned short* opart = opb + (size_t)sp * ((size_t)BATCH * NTOK * CH);
    float* lpart = lpb + (size_t)sp * (BATCH * NH * NTOK);

    const unsigned short* qbh = qT + ((size_t)(b * NH + h)) * NTOK * HD;
    const unsigned short* kbh = kT + ((size_t)(b * NH + h)) * NTOK * HD;
    const unsigned short* vbh = vv + ((size_t)(b * NH + h)) * HD * NTOK;

    __shared__ __align__(16) unsigned short kbuf[64 * 80];   // [key][hd]
    __shared__ __align__(16) unsigned short vbuf[64 * 72];   // [d][key]

    short8 aQ0 = *(const short8*)(qbh + (size_t)(n0 + l15) * HD + quad * 8);
    short8 aQ1 = *(const short8*)(qbh + (size_t)(n0 + l15) * HD + 32 + quad * 8);

    float l_p = 0.f;
    float4v o_acc[4];
    for (int ct = 0; ct < 4; ++ct)
        for (int r = 0; r < 4; ++r) o_acc[ct][r] = 0.f;

    for (int ms = kv0; ms < kv0 + NTOK / NSPLIT; ms += 64) {
        __syncthreads();
#pragma unroll
        for (int p = 0; p < 2; ++p) {        // K tile: 64 keys x 64 hd
            int slot = p * 256 + t;
            int r = slot >> 3, c = slot & 7;
            *(short8*)(kbuf + r * 80 + c * 8) =
                *(const short8*)(kbh + (size_t)(ms + r) * HD + c * 8);
        }
#pragma unroll
        for (int p = 0; p < 2; ++p) {        // V tile: 64 d x 64 keys
            int slot = p * 256 + t;
            int r = slot >> 3, c = slot & 7;
            *(short8*)(vbuf + r * 72 + c * 8) =
                *(const short8*)(vbh + (size_t)r * NTOK + ms + c * 8);
        }
        __syncthreads();

        float4v s[4];
#pragma unroll
        for (int nt = 0; nt < 4; ++nt) {
            int krow = nt * 16 + l15;
            short8 ak0 = *(const short8*)(kbuf + krow * 80 + quad * 8);
            short8 ak1 = *(const short8*)(kbuf + krow * 80 + 32 + quad * 8);
            float4v z;
            for (int r = 0; r < 4; ++r) z[r] = 0.f;
            z = __builtin_amdgcn_mfma_f32_16x16x32_bf16(ak0, aQ0, z, 0, 0, 0);
            z = __builtin_amdgcn_mfma_f32_16x16x32_bf16(ak1, aQ1, z, 0, 0, 0);
            s[nt] = z;
        }
        s4bf aP[4];
#pragma unroll
        for (int nt = 0; nt < 4; ++nt) {
            float e0 = __builtin_amdgcn_exp2f(s[nt][0]);
            float e1 = __builtin_amdgcn_exp2f(s[nt][1]);
            float e2 = __builtin_amdgcn_exp2f(s[nt][2]);
            float e3 = __builtin_amdgcn_exp2f(s[nt][3]);
            l_p += (e0 + e1) + (e2 + e3);
            union { s4bf v; unsigned u[2]; } c;
            c.u[0] = pk2bf(e0, e1);
            c.u[1] = pk2bf(e2, e3);
            aP[nt] = c.v;
        }
#pragma unroll
        for (int ct = 0; ct < 4; ++ct) {
#pragma unroll
            for (int nt = 0; nt < 4; ++nt) {
                s4bf bv = *(const s4bf*)(vbuf + (ct * 16 + l15) * 72 + nt * 16 + quad * 4);
                o_acc[ct] = __builtin_amdgcn_mfma_f32_16x16x16bf16_1k(aP[nt], bv, o_acc[ct], 0, 0, 0);
            }
        }
    }
    // reduce denom over the 4 quads (key blocks); q-row = l15
    l_p += __shfl_xor(l_p, 16, 64);
    l_p += __shfl_xor(l_p, 32, 64);
    // store unnormalized partial O (bf16): C-layout col=l15=d, row=quad*4+r=q-row
    for (int ct = 0; ct < 4; ++ct) {
        for (int r = 0; r < 4; ++r) {
            int n = n0 + quad * 4 + r;
            int cg = h * HD + ct * 16 + l15;
            opart[((size_t)b * NTOK + n) * CH + cg] = f2bf(o_acc[ct][r]);
        }
    }
    if (lane < 16)
        lpart[((size_t)(b * NH + h)) * NTOK + n0 + lane] = l_p;
}

// ---------------- Proj GEMM with fused split-combine + bias + residual ----------------
__global__ __launch_bounds__(256) void proj_gemm(const unsigned short* __restrict__ opb,
        const float* __restrict__ lpb, const unsigned short* __restrict__ wp,
        const float* __restrict__ proj_b, const float* __restrict__ x,
        float* __restrict__ out) {
    int nb = blockIdx.x;   // 0..63
    int cb = blockIdx.y;   // 0..3
    int b  = blockIdx.z;
    int t = threadIdx.x, wave = t >> 6, lane = t & 63;
    int l15 = lane & 15, quad = lane >> 4;
    int c0 = cb * 64 + wave * 16;
    const size_t OP = (size_t)BATCH * NTOK * CH;
    const size_t LP = (size_t)BATCH * NH * NTOK;

    __shared__ __align__(16) unsigned short bt[64 * 264];
    __shared__ float rl[64 * 4];

    short8 aW[8];
    {
        const unsigned short* wr = wp + (size_t)(c0 + l15) * CH + quad * 8;
        for (int kc = 0; kc < 8; ++kc) aW[kc] = *(const short8*)(wr + kc * 32);
    }
    // per-row, per-head reciprocal denominators (normalization must precede channel-sum)
    {
        int r = t >> 2, h = t & 3;
        size_t lidx = ((size_t)(b * NH + h)) * NTOK + nb * 64 + r;
        float ls = (lpb[lidx] + lpb[LP + lidx]) + (lpb[2 * LP + lidx] + lpb[3 * LP + lidx]);
        rl[r * 4 + h] = 1.0f / ls;
    }
    __syncthreads();
    // stage normalized O tile from the 4 split partials
    for (int p = 0; p < 8; ++p) {
        int slot = p * 256 + t;
        int r = slot >> 5, c = slot & 31;
        size_t base = ((size_t)b * NTOK + nb * 64 + r) * CH + c * 8;
        short8 o0 = *(const short8*)(opb + base);
        short8 o1 = *(const short8*)(opb + OP + base);
        short8 o2 = *(const short8*)(opb + 2 * OP + base);
        short8 o3 = *(const short8*)(opb + 3 * OP + base);
        float rinv = rl[r * 4 + (c >> 3)];
        short8 m;
        for (int j = 0; j < 8; ++j) {
            float f = (bf2f((unsigned short)o0[j]) + bf2f((unsigned short)o1[j]))
                    + (bf2f((unsigned short)o2[j]) + bf2f((unsigned short)o3[j]));
            m[j] = (short)f2bf(f * rinv);
        }
        *(short8*)(bt + r * 264 + c * 8) = m;
    }
    __syncthreads();

    float4v acc[4];
    for (int nt = 0; nt < 4; ++nt) for (int r = 0; r < 4; ++r) acc[nt][r] = 0.f;
    for (int kc = 0; kc < 8; ++kc) {
        for (int nt = 0; nt < 4; ++nt) {
            short8 pb = *(const short8*)(bt + (nt * 16 + l15) * 264 + kc * 32 + quad * 8);
            acc[nt] = __builtin_amdgcn_mfma_f32_16x16x32_bf16(aW[kc], pb, acc[nt], 0, 0, 0);
        }
    }
    for (int nt = 0; nt < 4; ++nt) {
        int n = nb * 64 + nt * 16 + l15;
        for (int r = 0; r < 4; ++r) {
            int cc = c0 + quad * 4 + r;
            size_t idx = ((size_t)(b * CH + cc)) * NTOK + n;
            out[idx] = acc[nt][r] + proj_b[cc] + x[idx];
        }
    }
}

extern "C" void kernel_launch(void* const* d_in, const int* in_sizes, int n_in,
                              void* d_out, int out_size, void* d_ws, size_t ws_size,
                              hipStream_t stream) {
    const float* x      = (const float*)d_in[0];
    const float* norm_w = (const float*)d_in[1];
    const float* norm_b = (const float*)d_in[2];
    const float* qkv_w  = (const float*)d_in[3];
    const float* qkv_b  = (const float*)d_in[4];
    const float* proj_w = (const float*)d_in[5];
    const float* proj_b = (const float*)d_in[6];
    float* out = (float*)d_out;

    char* ws = (char*)d_ws;
    float* psum  = (float*)ws;                       // 256 f
    float* psq   = (float*)(ws + 1024);              // 256 f
    float* bqs   = (float*)(ws + 4096);              // 768 f
    unsigned short* wqb = (unsigned short*)(ws + 8192);        // 3*256*256 bf16 -> 401408
    unsigned short* wpb = (unsigned short*)(ws + 401408);      // 256*256 bf16   -> 532480
    float* lpb = (float*)(ws + 532480);              // 4 * 2*4*4096 f = 512 KB
    const size_t MB4 = 4194304;
    unsigned short* hT  = (unsigned short*)(ws + 2097152);     // 4 MB (aliases op slot 0)
    unsigned short* opb = hT;                                  // 4 x 4 MB partials
    unsigned short* qT = (unsigned short*)(ws + 2097152 + 4 * MB4);
    unsigned short* kT = (unsigned short*)(ws + 2097152 + 5 * MB4);
    unsigned short* vv = (unsigned short*)(ws + 2097152 + 6 * MB4);

    prep<<<dim3(512), dim3(256), 0, stream>>>(x, qkv_w, qkv_b, proj_w, psum, psq, wqb, bqs, wpb);
    gn_norm<<<dim3(64, 8, BATCH), dim3(256), 0, stream>>>(x, norm_w, norm_b, psum, psq, hT);
    qkv_gemm<<<dim3(64, 6, BATCH), dim3(256), 0, stream>>>(hT, wqb, bqs, qT, kT, vv);
    attn_kernel<<<dim3(64, NH, BATCH * NSPLIT), dim3(256), 0, stream>>>(qT, kT, vv, opb, lpb);
    proj_gemm<<<dim3(64, 4, BATCH), dim3(256), 0, stream>>>(opb, lpb, wpb, proj_b, x, out);
}

// Round 9
// 161.934 us; speedup vs baseline: 1.0042x; 1.0042x over previous
//
#include <hip/hip_runtime.h>
#include <hip/hip_bf16.h>

#define BATCH 2
#define CH 256
#define NH 4
#define HD 64
#define NGROUP 8
#define CPG 32
#define NTOK 4096
#define EPSV 1e-5f
// scale = hd^-0.5 = 0.125, folded with log2(e) so P = exp2(q'.k)
#define QSCALE 0.1803368801111204f
#define NSPLIT 4

typedef __attribute__((ext_vector_type(8))) short short8;
typedef __attribute__((ext_vector_type(4))) short s4bf;
typedef __attribute__((ext_vector_type(4))) float float4v;

__device__ __forceinline__ unsigned short f2bf(float f) {
    union { float f; unsigned u; } v; v.f = f;
    unsigned r = v.u + 0x7FFF + ((v.u >> 16) & 1);
    return (unsigned short)(r >> 16);
}
__device__ __forceinline__ unsigned short f2bf_fast(float f) {
    union { float f; unsigned u; } v; v.f = f;
    return (unsigned short)((v.u + 0x8000u) >> 16);
}
__device__ __forceinline__ float bf2f(unsigned short u) {
    union { unsigned u; float f; } v; v.u = ((unsigned)u) << 16;
    return v.f;
}
// pack two f32 -> one VGPR holding two bf16
__device__ __forceinline__ unsigned pk2bf(float a, float b) {
#if __has_builtin(__builtin_amdgcn_cvt_pk_bf16_f32)
    typedef __attribute__((ext_vector_type(2))) __bf16 bf2v;
    bf2v p = __builtin_amdgcn_cvt_pk_bf16_f32(a, b);
    union { bf2v v; unsigned u; } c; c.v = p;
    return c.u;
#else
    return (unsigned)f2bf_fast(a) | ((unsigned)f2bf_fast(b) << 16);
#endif
}

// ---------------- prep: fused wcvt + gn_partial (independent work) ----------------
__global__ void prep(const float* __restrict__ x,
                     const float* __restrict__ qkv_w, const float* __restrict__ qkv_b,
                     const float* __restrict__ proj_w,
                     float* __restrict__ psum, float* __restrict__ psq,
                     unsigned short* __restrict__ wq, float* __restrict__ bq,
                     unsigned short* __restrict__ wp) {
    int bx = blockIdx.x;
    int t = threadIdx.x;
    if (bx < 256) {
        // -------- gn_partial --------
        int s = bx & 15, g = (bx >> 4) & 7, b = bx >> 7;
        const float* base = x + ((size_t)(b * CH + g * CPG)) * NTOK + (size_t)s * 8192;
        float sum = 0.f, sq = 0.f;
        const float4v* p4 = (const float4v*)base;
        for (int i = 0; i < 8; ++i) {
            float4v v = p4[t + i * 256];
            for (int j = 0; j < 4; ++j) { sum += v[j]; sq += v[j] * v[j]; }
        }
        for (int off = 32; off; off >>= 1) {
            sum += __shfl_down(sum, off, 64);
            sq  += __shfl_down(sq,  off, 64);
        }
        __shared__ float ls[8];
        int wave = t >> 6, lane = t & 63;
        if (lane == 0) { ls[wave * 2] = sum; ls[wave * 2 + 1] = sq; }
        __syncthreads();
        if (t == 0) {
            float S = 0.f, Q = 0.f;
            for (int w = 0; w < 4; ++w) { S += ls[w * 2]; Q += ls[w * 2 + 1]; }
            int idx = (b * NGROUP + g) * 16 + s;
            psum[idx] = S; psq[idx] = Q;
        }
    } else {
        // -------- wcvt --------
        int idx = (bx - 256) * 256 + t;
        int stride = 256 * 256;
        for (int i = idx; i < 3 * CH * CH; i += stride) {
            float f = qkv_w[i];
            if (i < CH * CH) f *= QSCALE;
            wq[i] = f2bf(f);
        }
        for (int i = idx; i < CH * CH; i += stride) wp[i] = f2bf(proj_w[i]);
        for (int i = idx; i < 3 * CH; i += stride) {
            float f = qkv_b[i];
            if (i < CH) f *= QSCALE;
            bq[i] = f;
        }
    }
}

// ---------------- GroupNorm: normalize + transpose (stats folded in) ----------------
__global__ void gn_norm(const float* __restrict__ x, const float* __restrict__ nw,
                        const float* __restrict__ nb_, const float* __restrict__ psum,
                        const float* __restrict__ psq, unsigned short* __restrict__ hT) {
    int t = threadIdx.x;
    int n = blockIdx.x * 64 + (t & 63);
    int g = blockIdx.y;                    // block covers exactly one group (32 ch)
    int cb = g * 32 + (t >> 6) * 8;
    int b = blockIdx.z;
    float S = 0.f, Q = 0.f;
    for (int s = 0; s < 16; ++s) {
        S += psum[(b * NGROUP + g) * 16 + s];
        Q += psq[(b * NGROUP + g) * 16 + s];
    }
    const float M = (float)(CPG * NTOK);
    float mean = S / M;
    float inv  = rsqrtf(Q / M - mean * mean + EPSV);
    short8 h8;
    for (int j = 0; j < 8; ++j) {
        int c = cb + j;
        float w  = nw[c] * inv;
        float bb = nb_[c] - mean * w;
        float v = x[((size_t)(b * CH + c)) * NTOK + n];
        h8[j] = (short)f2bf(v * w + bb);
    }
    *(short8*)(hT + ((size_t)b * NTOK + n) * CH + cb) = h8;
}

// ---------------- QKV GEMM: stage B once, 2 o-passes per block ----------------
__global__ __launch_bounds__(256) void qkv_gemm(const unsigned short* __restrict__ hT,
        const unsigned short* __restrict__ wq, const float* __restrict__ bq,
        unsigned short* __restrict__ qT, unsigned short* __restrict__ kT,
        unsigned short* __restrict__ vv) {
    int nb = blockIdx.x;       // 0..63 (n tile of 64)
    int og = blockIdx.y;       // 0..5  (o group of 128)
    int b  = blockIdx.z;
    int t = threadIdx.x;
    int wave = t >> 6, lane = t & 63;
    int l15 = lane & 15, quad = lane >> 4;

    __shared__ __align__(16) unsigned short bt[64 * 264];   // 132 dw stride (==4 mod 32)

    // stage B tile: 64 n-rows x 256 c
    for (int p = 0; p < 8; ++p) {
        int slot = p * 256 + t;
        int r = slot >> 5, c = slot & 31;
        *(short8*)(bt + r * 264 + c * 8) =
            *(const short8*)(hT + ((size_t)b * NTOK + nb * 64 + r) * CH + c * 8);
    }
    __syncthreads();

    for (int pass = 0; pass < 2; ++pass) {
        int o0 = og * 128 + pass * 64 + wave * 16;
        short8 aW[8];
        {
            const unsigned short* wr = wq + (size_t)(o0 + l15) * CH + quad * 8;
            for (int kc = 0; kc < 8; ++kc) aW[kc] = *(const short8*)(wr + kc * 32);
        }
        float4v acc[4];
        for (int nt = 0; nt < 4; ++nt) for (int r = 0; r < 4; ++r) acc[nt][r] = 0.f;
        for (int kc = 0; kc < 8; ++kc) {
            for (int nt = 0; nt < 4; ++nt) {
                short8 pb = *(const short8*)(bt + (nt * 16 + l15) * 264 + kc * 32 + quad * 8);
                acc[nt] = __builtin_amdgcn_mfma_f32_16x16x32_bf16(aW[kc], pb, acc[nt], 0, 0, 0);
            }
        }
        for (int nt = 0; nt < 4; ++nt) {
            int n = nb * 64 + nt * 16 + l15;
            for (int r = 0; r < 4; ++r) {
                int o = o0 + quad * 4 + r;
                float val = acc[nt][r] + bq[o];
                unsigned short bv = f2bf(val);
                int cch = o & 255;
                int seg = o >> 8;          // 0=q (pre-scaled), 1=k, 2=v
                int hh = cch >> 6, ci = cch & 63;
                if (seg == 0)      qT[(((size_t)b * NH + hh) * NTOK + n) * HD + ci] = bv;
                else if (seg == 1) kT[(((size_t)b * NH + hh) * NTOK + n) * HD + ci] = bv;
                else               vv[(((size_t)b * NH + hh) * HD + ci) * NTOK + n] = bv;
            }
        }
    }
}

// ---------------- Flash attention: S^T trick (register P->PV), 128-key tiles, split x4 ----
// (round-7 verified configuration: 128 q/block, 4 blocks/CU)
__global__ __launch_bounds__(256, 4) void attn_kernel(const unsigned short* __restrict__ qT,
        const unsigned short* __restrict__ kT, const unsigned short* __restrict__ vv,
        unsigned short* __restrict__ opb, float* __restrict__ lpb) {
    int nb = blockIdx.x;          // 0..31 : 128 query rows per block
    int h  = blockIdx.y;
    int zb = blockIdx.z;          // (b, split)
    int sp = zb & 3, b = zb >> 2;
    int t = threadIdx.x, wave = t >> 6, lane = t & 63;
    int l15 = lane & 15, quad = lane >> 4;
    int n0 = nb * 128 + wave * 32;     // wave owns 2 m-tiles of 16 rows
    int kv0 = sp * (NTOK / NSPLIT);

    unsigned short* opart = opb + (size_t)sp * ((size_t)BATCH * NTOK * CH);
    float* lpart = lpb + (size_t)sp * (BATCH * NH * NTOK);

    const unsigned short* qbh = qT + ((size_t)(b * NH + h)) * NTOK * HD;
    const unsigned short* kbh = kT + ((size_t)(b * NH + h)) * NTOK * HD;
    const unsigned short* vbh = vv + ((size_t)(b * NH + h)) * HD * NTOK;

    __shared__ __align__(16) unsigned short kbuf[128 * 80];
    __shared__ __align__(16) unsigned short vbuf[64 * 136];

    short8 aQ[2][2];   // B-fragment of QK: B[q-row=l15][hd k=quad*8+j]
    for (int mt = 0; mt < 2; ++mt) {
        aQ[mt][0] = *(const short8*)(qbh + (size_t)(n0 + mt * 16 + l15) * HD + quad * 8);
        aQ[mt][1] = *(const short8*)(qbh + (size_t)(n0 + mt * 16 + l15) * HD + 32 + quad * 8);
    }

    float l_p[2] = {0.f, 0.f};         // per-lane partial denom (q-row = l15)
    float4v o_acc[2][4];
    for (int mt = 0; mt < 2; ++mt)
        for (int ct = 0; ct < 4; ++ct)
            for (int r = 0; r < 4; ++r) o_acc[mt][ct][r] = 0.f;

    for (int ms = kv0; ms < kv0 + NTOK / NSPLIT; ms += 128) {
        __syncthreads();
#pragma unroll
        for (int p = 0; p < 4; ++p) {
            int slot = p * 256 + t;
            int r = slot >> 3, c = slot & 7;
            short8 kd = *(const short8*)(kbh + (size_t)(ms + r) * HD + c * 8);
            *(short8*)(kbuf + r * 80 + c * 8) = kd;
        }
#pragma unroll
        for (int p = 0; p < 4; ++p) {
            int slot = p * 256 + t;
            int r = slot >> 4, c = slot & 15;
            short8 vd = *(const short8*)(vbh + (size_t)r * NTOK + ms + c * 8);
            *(short8*)(vbuf + r * 136 + c * 8) = vd;
        }
        __syncthreads();

#pragma unroll
        for (int kh = 0; kh < 2; ++kh) {      // two 64-key halves
            float4v s[2][4];
#pragma unroll
            for (int nt = 0; nt < 4; ++nt) {
                int krow = kh * 64 + nt * 16 + l15;
                short8 ak0 = *(const short8*)(kbuf + krow * 80 + quad * 8);
                short8 ak1 = *(const short8*)(kbuf + krow * 80 + 32 + quad * 8);
#pragma unroll
                for (int mt = 0; mt < 2; ++mt) {
                    float4v z;
                    for (int r = 0; r < 4; ++r) z[r] = 0.f;
                    z = __builtin_amdgcn_mfma_f32_16x16x32_bf16(ak0, aQ[mt][0], z, 0, 0, 0);
                    z = __builtin_amdgcn_mfma_f32_16x16x32_bf16(ak1, aQ[mt][1], z, 0, 0, 0);
                    s[mt][nt] = z;
                }
            }
            s4bf aP[2][4];
#pragma unroll
            for (int mt = 0; mt < 2; ++mt) {
#pragma unroll
                for (int nt = 0; nt < 4; ++nt) {
                    float e0 = __builtin_amdgcn_exp2f(s[mt][nt][0]);
                    float e1 = __builtin_amdgcn_exp2f(s[mt][nt][1]);
                    float e2 = __builtin_amdgcn_exp2f(s[mt][nt][2]);
                    float e3 = __builtin_amdgcn_exp2f(s[mt][nt][3]);
                    l_p[mt] += (e0 + e1) + (e2 + e3);
                    union { s4bf v; unsigned u[2]; } c;
                    c.u[0] = pk2bf(e0, e1);
                    c.u[1] = pk2bf(e2, e3);
                    aP[mt][nt] = c.v;
                }
            }
#pragma unroll
            for (int ct = 0; ct < 4; ++ct) {
#pragma unroll
                for (int nt = 0; nt < 4; ++nt) {
                    s4bf bv = *(const s4bf*)(vbuf + (ct * 16 + l15) * 136 + kh * 64 + nt * 16 + quad * 4);
#pragma unroll
                    for (int mt = 0; mt < 2; ++mt)
                        o_acc[mt][ct] = __builtin_amdgcn_mfma_f32_16x16x16bf16_1k(aP[mt][nt], bv, o_acc[mt][ct], 0, 0, 0);
                }
            }
        }
    }
    // reduce denom over the 4 quads (key blocks); q-row = l15
    for (int mt = 0; mt < 2; ++mt) {
        l_p[mt] += __shfl_xor(l_p[mt], 16, 64);
        l_p[mt] += __shfl_xor(l_p[mt], 32, 64);
    }
    // store unnormalized partial O (bf16): C-layout col=l15=d, row=quad*4+r=q-row
    for (int mt = 0; mt < 2; ++mt) {
        for (int ct = 0; ct < 4; ++ct) {
            for (int r = 0; r < 4; ++r) {
                int n = n0 + mt * 16 + quad * 4 + r;
                int cg = h * HD + ct * 16 + l15;
                opart[((size_t)b * NTOK + n) * CH + cg] = f2bf(o_acc[mt][ct][r]);
            }
        }
        if (lane < 16)
            lpart[((size_t)(b * NH + h)) * NTOK + n0 + mt * 16 + lane] = l_p[mt];
    }
}

// ---------------- Proj GEMM: stage combined tile once, 2 c-passes + bias + residual ----
__global__ __launch_bounds__(256) void proj_gemm(const unsigned short* __restrict__ opb,
        const float* __restrict__ lpb, const unsigned short* __restrict__ wp,
        const float* __restrict__ proj_b, const float* __restrict__ x,
        float* __restrict__ out) {
    int nb = blockIdx.x;   // 0..63
    int cg = blockIdx.y;   // 0..1 (c group of 128)
    int b  = blockIdx.z;
    int t = threadIdx.x, wave = t >> 6, lane = t & 63;
    int l15 = lane & 15, quad = lane >> 4;
    const size_t OP = (size_t)BATCH * NTOK * CH;
    const size_t LP = (size_t)BATCH * NH * NTOK;

    __shared__ __align__(16) unsigned short bt[64 * 264];
    __shared__ float rl[64 * 4];

    // per-row, per-head reciprocal denominators (normalization must precede channel-sum)
    {
        int r = t >> 2, h = t & 3;
        size_t lidx = ((size_t)(b * NH + h)) * NTOK + nb * 64 + r;
        float ls = (lpb[lidx] + lpb[LP + lidx]) + (lpb[2 * LP + lidx] + lpb[3 * LP + lidx]);
        rl[r * 4 + h] = 1.0f / ls;
    }
    __syncthreads();
    // stage normalized O tile from the 4 split partials (once per block)
    for (int p = 0; p < 8; ++p) {
        int slot = p * 256 + t;
        int r = slot >> 5, c = slot & 31;
        size_t base = ((size_t)b * NTOK + nb * 64 + r) * CH + c * 8;
        short8 o0 = *(const short8*)(opb + base);
        short8 o1 = *(const short8*)(opb + OP + base);
        short8 o2 = *(const short8*)(opb + 2 * OP + base);
        short8 o3 = *(const short8*)(opb + 3 * OP + base);
        float rinv = rl[r * 4 + (c >> 3)];
        short8 m;
        for (int j = 0; j < 8; ++j) {
            float f = (bf2f((unsigned short)o0[j]) + bf2f((unsigned short)o1[j]))
                    + (bf2f((unsigned short)o2[j]) + bf2f((unsigned short)o3[j]));
            m[j] = (short)f2bf(f * rinv);
        }
        *(short8*)(bt + r * 264 + c * 8) = m;
    }
    __syncthreads();

    for (int pass = 0; pass < 2; ++pass) {
        int c0 = cg * 128 + pass * 64 + wave * 16;
        short8 aW[8];
        {
            const unsigned short* wr = wp + (size_t)(c0 + l15) * CH + quad * 8;
            for (int kc = 0; kc < 8; ++kc) aW[kc] = *(const short8*)(wr + kc * 32);
        }
        float4v acc[4];
        for (int nt = 0; nt < 4; ++nt) for (int r = 0; r < 4; ++r) acc[nt][r] = 0.f;
        for (int kc = 0; kc < 8; ++kc) {
            for (int nt = 0; nt < 4; ++nt) {
                short8 pb = *(const short8*)(bt + (nt * 16 + l15) * 264 + kc * 32 + quad * 8);
                acc[nt] = __builtin_amdgcn_mfma_f32_16x16x32_bf16(aW[kc], pb, acc[nt], 0, 0, 0);
            }
        }
        for (int nt = 0; nt < 4; ++nt) {
            int n = nb * 64 + nt * 16 + l15;
            for (int r = 0; r < 4; ++r) {
                int cc = c0 + quad * 4 + r;
                size_t idx = ((size_t)(b * CH + cc)) * NTOK + n;
                out[idx] = acc[nt][r] + proj_b[cc] + x[idx];
            }
        }
    }
}

extern "C" void kernel_launch(void* const* d_in, const int* in_sizes, int n_in,
                              void* d_out, int out_size, void* d_ws, size_t ws_size,
                              hipStream_t stream) {
    const float* x      = (const float*)d_in[0];
    const float* norm_w = (const float*)d_in[1];
    const float* norm_b = (const float*)d_in[2];
    const float* qkv_w  = (const float*)d_in[3];
    const float* qkv_b  = (const float*)d_in[4];
    const float* proj_w = (const float*)d_in[5];
    const float* proj_b = (const float*)d_in[6];
    float* out = (float*)d_out;

    char* ws = (char*)d_ws;
    float* psum  = (float*)ws;                       // 256 f
    float* psq   = (float*)(ws + 1024);              // 256 f
    float* bqs   = (float*)(ws + 4096);              // 768 f
    unsigned short* wqb = (unsigned short*)(ws + 8192);        // 3*256*256 bf16 -> 401408
    unsigned short* wpb = (unsigned short*)(ws + 401408);      // 256*256 bf16   -> 532480
    float* lpb = (float*)(ws + 532480);              // 4 * 2*4*4096 f = 512 KB
    const size_t MB4 = 4194304;
    unsigned short* hT  = (unsigned short*)(ws + 2097152);     // 4 MB (aliases op slot 0)
    unsigned short* opb = hT;                                  // 4 x 4 MB partials
    unsigned short* qT = (unsigned short*)(ws + 2097152 + 4 * MB4);
    unsigned short* kT = (unsigned short*)(ws + 2097152 + 5 * MB4);
    unsigned short* vv = (unsigned short*)(ws + 2097152 + 6 * MB4);

    prep<<<dim3(512), dim3(256), 0, stream>>>(x, qkv_w, qkv_b, proj_w, psum, psq, wqb, bqs, wpb);
    gn_norm<<<dim3(64, 8, BATCH), dim3(256), 0, stream>>>(x, norm_w, norm_b, psum, psq, hT);
    qkv_gemm<<<dim3(64, 6, BATCH), dim3(256), 0, stream>>>(hT, wqb, bqs, qT, kT, vv);
    attn_kernel<<<dim3(32, NH, BATCH * NSPLIT), dim3(256), 0, stream>>>(qT, kT, vv, opb, lpb);
    proj_gemm<<<dim3(64, 2, BATCH), dim3(256), 0, stream>>>(opb, lpb, wpb, proj_b, x, out);
}

// Round 10
// 155.427 us; speedup vs baseline: 1.0463x; 1.0419x over previous
//
#include <hip/hip_runtime.h>
#include <hip/hip_bf16.h>

#define BATCH 2
#define CH 256
#define NH 4
#define HD 64
#define NGROUP 8
#define CPG 32
#define NTOK 4096
#define EPSV 1e-5f
// scale = hd^-0.5 = 0.125, folded with log2(e) so P = exp2(q'.k)
#define QSCALE 0.1803368801111204f
#define NSPLIT 4

typedef __attribute__((ext_vector_type(8))) short short8;
typedef __attribute__((ext_vector_type(4))) short s4bf;
typedef __attribute__((ext_vector_type(4))) float float4v;

__device__ __forceinline__ unsigned short f2bf(float f) {
    union { float f; unsigned u; } v; v.f = f;
    unsigned r = v.u + 0x7FFF + ((v.u >> 16) & 1);
    return (unsigned short)(r >> 16);
}
__device__ __forceinline__ unsigned short f2bf_fast(float f) {
    union { float f; unsigned u; } v; v.f = f;
    return (unsigned short)((v.u + 0x8000u) >> 16);
}
__device__ __forceinline__ float bf2f(unsigned short u) {
    union { unsigned u; float f; } v; v.u = ((unsigned)u) << 16;
    return v.f;
}
// pack two f32 -> one VGPR holding two bf16
__device__ __forceinline__ unsigned pk2bf(float a, float b) {
#if __has_builtin(__builtin_amdgcn_cvt_pk_bf16_f32)
    typedef __attribute__((ext_vector_type(2))) __bf16 bf2v;
    bf2v p = __builtin_amdgcn_cvt_pk_bf16_f32(a, b);
    union { bf2v v; unsigned u; } c; c.v = p;
    return c.u;
#else
    return (unsigned)f2bf_fast(a) | ((unsigned)f2bf_fast(b) << 16);
#endif
}

// ---------------- prep: fused wcvt + gn_partial (independent work) ----------------
__global__ void prep(const float* __restrict__ x,
                     const float* __restrict__ qkv_w, const float* __restrict__ qkv_b,
                     const float* __restrict__ proj_w,
                     float* __restrict__ psum, float* __restrict__ psq,
                     unsigned short* __restrict__ wq, float* __restrict__ bq,
                     unsigned short* __restrict__ wp) {
    int bx = blockIdx.x;
    int t = threadIdx.x;
    if (bx < 256) {
        // -------- gn_partial --------
        int s = bx & 15, g = (bx >> 4) & 7, b = bx >> 7;
        const float* base = x + ((size_t)(b * CH + g * CPG)) * NTOK + (size_t)s * 8192;
        float sum = 0.f, sq = 0.f;
        const float4v* p4 = (const float4v*)base;
        for (int i = 0; i < 8; ++i) {
            float4v v = p4[t + i * 256];
            for (int j = 0; j < 4; ++j) { sum += v[j]; sq += v[j] * v[j]; }
        }
        for (int off = 32; off; off >>= 1) {
            sum += __shfl_down(sum, off, 64);
            sq  += __shfl_down(sq,  off, 64);
        }
        __shared__ float ls[8];
        int wave = t >> 6, lane = t & 63;
        if (lane == 0) { ls[wave * 2] = sum; ls[wave * 2 + 1] = sq; }
        __syncthreads();
        if (t == 0) {
            float S = 0.f, Q = 0.f;
            for (int w = 0; w < 4; ++w) { S += ls[w * 2]; Q += ls[w * 2 + 1]; }
            int idx = (b * NGROUP + g) * 16 + s;
            psum[idx] = S; psq[idx] = Q;
        }
    } else {
        // -------- wcvt --------
        int idx = (bx - 256) * 256 + t;
        int stride = 256 * 256;
        for (int i = idx; i < 3 * CH * CH; i += stride) {
            float f = qkv_w[i];
            if (i < CH * CH) f *= QSCALE;
            wq[i] = f2bf(f);
        }
        for (int i = idx; i < CH * CH; i += stride) wp[i] = f2bf(proj_w[i]);
        for (int i = idx; i < 3 * CH; i += stride) {
            float f = qkv_b[i];
            if (i < CH) f *= QSCALE;
            bq[i] = f;
        }
    }
}

// ---------------- QKV GEMM with fused GroupNorm staging, 2 o-passes per block ------
__global__ __launch_bounds__(256) void qkv_gemm(const float* __restrict__ x,
        const float* __restrict__ nw, const float* __restrict__ nb_,
        const float* __restrict__ psum, const float* __restrict__ psq,
        const unsigned short* __restrict__ wq, const float* __restrict__ bq,
        unsigned short* __restrict__ qT, unsigned short* __restrict__ kT,
        unsigned short* __restrict__ vv) {
    int nb = blockIdx.x;       // 0..63 (n tile of 64)
    int og = blockIdx.y;       // 0..5  (o group of 128)
    int b  = blockIdx.z;
    int t = threadIdx.x;
    int wave = t >> 6, lane = t & 63;
    int l15 = lane & 15, quad = lane >> 4;

    __shared__ __align__(16) unsigned short bt[64 * 264];   // 132 dw stride (==4 mod 32)

    // --- fused GroupNorm staging: thread t = channel t, 64 n-rows ---
    {
        int c = t;
        int g = c >> 5;
        float S = 0.f, Q = 0.f;
        for (int s = 0; s < 16; ++s) {
            S += psum[(b * NGROUP + g) * 16 + s];
            Q += psq[(b * NGROUP + g) * 16 + s];
        }
        const float M = (float)(CPG * NTOK);
        float mean = S / M;
        float inv  = rsqrtf(Q / M - mean * mean + EPSV);
        float w  = nw[c] * inv;
        float bb = nb_[c] - mean * w;
        const float4v* px = (const float4v*)(x + ((size_t)(b * CH + c)) * NTOK + nb * 64);
        for (int i = 0; i < 16; ++i) {
            float4v v = px[i];
            for (int j = 0; j < 4; ++j)
                bt[(i * 4 + j) * 264 + c] = f2bf(v[j] * w + bb);
        }
    }
    __syncthreads();

    for (int pass = 0; pass < 2; ++pass) {
        int o0 = og * 128 + pass * 64 + wave * 16;
        short8 aW[8];
        {
            const unsigned short* wr = wq + (size_t)(o0 + l15) * CH + quad * 8;
            for (int kc = 0; kc < 8; ++kc) aW[kc] = *(const short8*)(wr + kc * 32);
        }
        float4v acc[4];
        for (int nt = 0; nt < 4; ++nt) for (int r = 0; r < 4; ++r) acc[nt][r] = 0.f;
        for (int kc = 0; kc < 8; ++kc) {
            for (int nt = 0; nt < 4; ++nt) {
                short8 pb = *(const short8*)(bt + (nt * 16 + l15) * 264 + kc * 32 + quad * 8);
                acc[nt] = __builtin_amdgcn_mfma_f32_16x16x32_bf16(aW[kc], pb, acc[nt], 0, 0, 0);
            }
        }
        for (int nt = 0; nt < 4; ++nt) {
            int n = nb * 64 + nt * 16 + l15;
            for (int r = 0; r < 4; ++r) {
                int o = o0 + quad * 4 + r;
                float val = acc[nt][r] + bq[o];
                unsigned short bv = f2bf(val);
                int cch = o & 255;
                int seg = o >> 8;          // 0=q (pre-scaled), 1=k, 2=v
                int hh = cch >> 6, ci = cch & 63;
                if (seg == 0)      qT[(((size_t)b * NH + hh) * NTOK + n) * HD + ci] = bv;
                else if (seg == 1) kT[(((size_t)b * NH + hh) * NTOK + n) * HD + ci] = bv;
                else               vv[(((size_t)b * NH + hh) * HD + ci) * NTOK + n] = bv;
            }
        }
    }
}

// ---------------- Flash attention: S^T trick (register P->PV), 128-key tiles, split x4 ----
// (round-7 verified configuration: 128 q/block, 4 blocks/CU)
__global__ __launch_bounds__(256, 4) void attn_kernel(const unsigned short* __restrict__ qT,
        const unsigned short* __restrict__ kT, const unsigned short* __restrict__ vv,
        unsigned short* __restrict__ opb, float* __restrict__ lpb) {
    int nb = blockIdx.x;          // 0..31 : 128 query rows per block
    int h  = blockIdx.y;
    int zb = blockIdx.z;          // (b, split)
    int sp = zb & 3, b = zb >> 2;
    int t = threadIdx.x, wave = t >> 6, lane = t & 63;
    int l15 = lane & 15, quad = lane >> 4;
    int n0 = nb * 128 + wave * 32;     // wave owns 2 m-tiles of 16 rows
    int kv0 = sp * (NTOK / NSPLIT);

    unsigned short* opart = opb + (size_t)sp * ((size_t)BATCH * NTOK * CH);
    float* lpart = lpb + (size_t)sp * (BATCH * NH * NTOK);

    const unsigned short* qbh = qT + ((size_t)(b * NH + h)) * NTOK * HD;
    const unsigned short* kbh = kT + ((size_t)(b * NH + h)) * NTOK * HD;
    const unsigned short* vbh = vv + ((size_t)(b * NH + h)) * HD * NTOK;

    __shared__ __align__(16) unsigned short kbuf[128 * 80];
    __shared__ __align__(16) unsigned short vbuf[64 * 136];

    short8 aQ[2][2];   // B-fragment of QK: B[q-row=l15][hd k=quad*8+j]
    for (int mt = 0; mt < 2; ++mt) {
        aQ[mt][0] = *(const short8*)(qbh + (size_t)(n0 + mt * 16 + l15) * HD + quad * 8);
        aQ[mt][1] = *(const short8*)(qbh + (size_t)(n0 + mt * 16 + l15) * HD + 32 + quad * 8);
    }

    float l_p[2] = {0.f, 0.f};         // per-lane partial denom (q-row = l15)
    float4v o_acc[2][4];
    for (int mt = 0; mt < 2; ++mt)
        for (int ct = 0; ct < 4; ++ct)
            for (int r = 0; r < 4; ++r) o_acc[mt][ct][r] = 0.f;

    for (int ms = kv0; ms < kv0 + NTOK / NSPLIT; ms += 128) {
        __syncthreads();
#pragma unroll
        for (int p = 0; p < 4; ++p) {
            int slot = p * 256 + t;
            int r = slot >> 3, c = slot & 7;
            short8 kd = *(const short8*)(kbh + (size_t)(ms + r) * HD + c * 8);
            *(short8*)(kbuf + r * 80 + c * 8) = kd;
        }
#pragma unroll
        for (int p = 0; p < 4; ++p) {
            int slot = p * 256 + t;
            int r = slot >> 4, c = slot & 15;
            short8 vd = *(const short8*)(vbh + (size_t)r * NTOK + ms + c * 8);
            *(short8*)(vbuf + r * 136 + c * 8) = vd;
        }
        __syncthreads();

#pragma unroll
        for (int kh = 0; kh < 2; ++kh) {      // two 64-key halves
            float4v s[2][4];
#pragma unroll
            for (int nt = 0; nt < 4; ++nt) {
                int krow = kh * 64 + nt * 16 + l15;
                short8 ak0 = *(const short8*)(kbuf + krow * 80 + quad * 8);
                short8 ak1 = *(const short8*)(kbuf + krow * 80 + 32 + quad * 8);
#pragma unroll
                for (int mt = 0; mt < 2; ++mt) {
                    float4v z;
                    for (int r = 0; r < 4; ++r) z[r] = 0.f;
                    z = __builtin_amdgcn_mfma_f32_16x16x32_bf16(ak0, aQ[mt][0], z, 0, 0, 0);
                    z = __builtin_amdgcn_mfma_f32_16x16x32_bf16(ak1, aQ[mt][1], z, 0, 0, 0);
                    s[mt][nt] = z;
                }
            }
            s4bf aP[2][4];
#pragma unroll
            for (int mt = 0; mt < 2; ++mt) {
#pragma unroll
                for (int nt = 0; nt < 4; ++nt) {
                    float e0 = __builtin_amdgcn_exp2f(s[mt][nt][0]);
                    float e1 = __builtin_amdgcn_exp2f(s[mt][nt][1]);
                    float e2 = __builtin_amdgcn_exp2f(s[mt][nt][2]);
                    float e3 = __builtin_amdgcn_exp2f(s[mt][nt][3]);
                    l_p[mt] += (e0 + e1) + (e2 + e3);
                    union { s4bf v; unsigned u[2]; } c;
                    c.u[0] = pk2bf(e0, e1);
                    c.u[1] = pk2bf(e2, e3);
                    aP[mt][nt] = c.v;
                }
            }
#pragma unroll
            for (int ct = 0; ct < 4; ++ct) {
#pragma unroll
                for (int nt = 0; nt < 4; ++nt) {
                    s4bf bv = *(const s4bf*)(vbuf + (ct * 16 + l15) * 136 + kh * 64 + nt * 16 + quad * 4);
#pragma unroll
                    for (int mt = 0; mt < 2; ++mt)
                        o_acc[mt][ct] = __builtin_amdgcn_mfma_f32_16x16x16bf16_1k(aP[mt][nt], bv, o_acc[mt][ct], 0, 0, 0);
                }
            }
        }
    }
    // reduce denom over the 4 quads (key blocks); q-row = l15
    for (int mt = 0; mt < 2; ++mt) {
        l_p[mt] += __shfl_xor(l_p[mt], 16, 64);
        l_p[mt] += __shfl_xor(l_p[mt], 32, 64);
    }
    // store unnormalized partial O (bf16): C-layout col=l15=d, row=quad*4+r=q-row
    for (int mt = 0; mt < 2; ++mt) {
        for (int ct = 0; ct < 4; ++ct) {
            for (int r = 0; r < 4; ++r) {
                int n = n0 + mt * 16 + quad * 4 + r;
                int cg = h * HD + ct * 16 + l15;
                opart[((size_t)b * NTOK + n) * CH + cg] = f2bf(o_acc[mt][ct][r]);
            }
        }
        if (lane < 16)
            lpart[((size_t)(b * NH + h)) * NTOK + n0 + mt * 16 + lane] = l_p[mt];
    }
}

// ---------------- Proj GEMM with fused split-combine + bias + residual (R7 config) ----
__global__ __launch_bounds__(256) void proj_gemm(const unsigned short* __restrict__ opb,
        const float* __restrict__ lpb, const unsigned short* __restrict__ wp,
        const float* __restrict__ proj_b, const float* __restrict__ x,
        float* __restrict__ out) {
    int nb = blockIdx.x;   // 0..63
    int cb = blockIdx.y;   // 0..3
    int b  = blockIdx.z;
    int t = threadIdx.x, wave = t >> 6, lane = t & 63;
    int l15 = lane & 15, quad = lane >> 4;
    int c0 = cb * 64 + wave * 16;
    const size_t OP = (size_t)BATCH * NTOK * CH;
    const size_t LP = (size_t)BATCH * NH * NTOK;

    __shared__ __align__(16) unsigned short bt[64 * 264];
    __shared__ float rl[64 * 4];

    short8 aW[8];
    {
        const unsigned short* wr = wp + (size_t)(c0 + l15) * CH + quad * 8;
        for (int kc = 0; kc < 8; ++kc) aW[kc] = *(const short8*)(wr + kc * 32);
    }
    // per-row, per-head reciprocal denominators (normalization must precede channel-sum)
    {
        int r = t >> 2, h = t & 3;
        size_t lidx = ((size_t)(b * NH + h)) * NTOK + nb * 64 + r;
        float ls = (lpb[lidx] + lpb[LP + lidx]) + (lpb[2 * LP + lidx] + lpb[3 * LP + lidx]);
        rl[r * 4 + h] = 1.0f / ls;
    }
    __syncthreads();
    // stage normalized O tile from the 4 split partials
    for (int p = 0; p < 8; ++p) {
        int slot = p * 256 + t;
        int r = slot >> 5, c = slot & 31;
        size_t base = ((size_t)b * NTOK + nb * 64 + r) * CH + c * 8;
        short8 o0 = *(const short8*)(opb + base);
        short8 o1 = *(const short8*)(opb + OP + base);
        short8 o2 = *(const short8*)(opb + 2 * OP + base);
        short8 o3 = *(const short8*)(opb + 3 * OP + base);
        float rinv = rl[r * 4 + (c >> 3)];
        short8 m;
        for (int j = 0; j < 8; ++j) {
            float f = (bf2f((unsigned short)o0[j]) + bf2f((unsigned short)o1[j]))
                    + (bf2f((unsigned short)o2[j]) + bf2f((unsigned short)o3[j]));
            m[j] = (short)f2bf(f * rinv);
        }
        *(short8*)(bt + r * 264 + c * 8) = m;
    }
    __syncthreads();

    float4v acc[4];
    for (int nt = 0; nt < 4; ++nt) for (int r = 0; r < 4; ++r) acc[nt][r] = 0.f;
    for (int kc = 0; kc < 8; ++kc) {
        for (int nt = 0; nt < 4; ++nt) {
            short8 pb = *(const short8*)(bt + (nt * 16 + l15) * 264 + kc * 32 + quad * 8);
            acc[nt] = __builtin_amdgcn_mfma_f32_16x16x32_bf16(aW[kc], pb, acc[nt], 0, 0, 0);
        }
    }
    for (int nt = 0; nt < 4; ++nt) {
        int n = nb * 64 + nt * 16 + l15;
        for (int r = 0; r < 4; ++r) {
            int cc = c0 + quad * 4 + r;
            size_t idx = ((size_t)(b * CH + cc)) * NTOK + n;
            out[idx] = acc[nt][r] + proj_b[cc] + x[idx];
        }
    }
}

extern "C" void kernel_launch(void* const* d_in, const int* in_sizes, int n_in,
                              void* d_out, int out_size, void* d_ws, size_t ws_size,
                              hipStream_t stream) {
    const float* x      = (const float*)d_in[0];
    const float* norm_w = (const float*)d_in[1];
    const float* norm_b = (const float*)d_in[2];
    const float* qkv_w  = (const float*)d_in[3];
    const float* qkv_b  = (const float*)d_in[4];
    const float* proj_w = (const float*)d_in[5];
    const float* proj_b = (const float*)d_in[6];
    float* out = (float*)d_out;

    char* ws = (char*)d_ws;
    float* psum  = (float*)ws;                       // 256 f
    float* psq   = (float*)(ws + 1024);              // 256 f
    float* bqs   = (float*)(ws + 4096);              // 768 f
    unsigned short* wqb = (unsigned short*)(ws + 8192);        // 3*256*256 bf16 -> 401408
    unsigned short* wpb = (unsigned short*)(ws + 401408);      // 256*256 bf16   -> 532480
    float* lpb = (float*)(ws + 532480);              // 4 * 2*4*4096 f = 512 KB
    const size_t MB4 = 4194304;
    unsigned short* opb = (unsigned short*)(ws + 2097152);     // 4 x 4 MB partials
    unsigned short* qT = (unsigned short*)(ws + 2097152 + 4 * MB4);
    unsigned short* kT = (unsigned short*)(ws + 2097152 + 5 * MB4);
    unsigned short* vv = (unsigned short*)(ws + 2097152 + 6 * MB4);

    prep<<<dim3(512), dim3(256), 0, stream>>>(x, qkv_w, qkv_b, proj_w, psum, psq, wqb, bqs, wpb);
    qkv_gemm<<<dim3(64, 6, BATCH), dim3(256), 0, stream>>>(x, norm_w, norm_b, psum, psq, wqb, bqs, qT, kT, vv);
    attn_kernel<<<dim3(32, NH, BATCH * NSPLIT), dim3(256), 0, stream>>>(qT, kT, vv, opb, lpb);
    proj_gemm<<<dim3(64, 4, BATCH), dim3(256), 0, stream>>>(opb, lpb, wpb, proj_b, x, out);
}

// Round 11
// 154.797 us; speedup vs baseline: 1.0505x; 1.0041x over previous
//
#include <hip/hip_runtime.h>
#include <hip/hip_bf16.h>

#define BATCH 2
#define CH 256
#define NH 4
#define HD 64
#define NGROUP 8
#define CPG 32
#define NTOK 4096
#define EPSV 1e-5f
// scale = hd^-0.5 = 0.125, folded with log2(e) so P = exp2(q'.k)
#define QSCALE 0.1803368801111204f
#define NSPLIT 4

typedef __attribute__((ext_vector_type(8))) short short8;
typedef __attribute__((ext_vector_type(4))) short s4bf;
typedef __attribute__((ext_vector_type(4))) float float4v;

__device__ __forceinline__ unsigned short f2bf(float f) {
    union { float f; unsigned u; } v; v.f = f;
    unsigned r = v.u + 0x7FFF + ((v.u >> 16) & 1);
    return (unsigned short)(r >> 16);
}
__device__ __forceinline__ unsigned short f2bf_fast(float f) {
    union { float f; unsigned u; } v; v.f = f;
    return (unsigned short)((v.u + 0x8000u) >> 16);
}
__device__ __forceinline__ float bf2f(unsigned short u) {
    union { unsigned u; float f; } v; v.u = ((unsigned)u) << 16;
    return v.f;
}
// pack two f32 -> one VGPR holding two bf16
__device__ __forceinline__ unsigned pk2bf(float a, float b) {
#if __has_builtin(__builtin_amdgcn_cvt_pk_bf16_f32)
    typedef __attribute__((ext_vector_type(2))) __bf16 bf2v;
    bf2v p = __builtin_amdgcn_cvt_pk_bf16_f32(a, b);
    union { bf2v v; unsigned u; } c; c.v = p;
    return c.u;
#else
    return (unsigned)f2bf_fast(a) | ((unsigned)f2bf_fast(b) << 16);
#endif
}

// ---------------- prep: fused wcvt + gn_partial (independent work) ----------------
__global__ void prep(const float* __restrict__ x,
                     const float* __restrict__ qkv_w, const float* __restrict__ qkv_b,
                     const float* __restrict__ proj_w,
                     float* __restrict__ psum, float* __restrict__ psq,
                     unsigned short* __restrict__ wq, float* __restrict__ bq,
                     unsigned short* __restrict__ wp) {
    int bx = blockIdx.x;
    int t = threadIdx.x;
    if (bx < 256) {
        // -------- gn_partial --------
        int s = bx & 15, g = (bx >> 4) & 7, b = bx >> 7;
        const float* base = x + ((size_t)(b * CH + g * CPG)) * NTOK + (size_t)s * 8192;
        float sum = 0.f, sq = 0.f;
        const float4v* p4 = (const float4v*)base;
        for (int i = 0; i < 8; ++i) {
            float4v v = p4[t + i * 256];
            for (int j = 0; j < 4; ++j) { sum += v[j]; sq += v[j] * v[j]; }
        }
        for (int off = 32; off; off >>= 1) {
            sum += __shfl_down(sum, off, 64);
            sq  += __shfl_down(sq,  off, 64);
        }
        __shared__ float ls[8];
        int wave = t >> 6, lane = t & 63;
        if (lane == 0) { ls[wave * 2] = sum; ls[wave * 2 + 1] = sq; }
        __syncthreads();
        if (t == 0) {
            float S = 0.f, Q = 0.f;
            for (int w = 0; w < 4; ++w) { S += ls[w * 2]; Q += ls[w * 2 + 1]; }
            int idx = (b * NGROUP + g) * 16 + s;
            psum[idx] = S; psq[idx] = Q;
        }
    } else {
        // -------- wcvt --------
        int idx = (bx - 256) * 256 + t;
        int stride = 256 * 256;
        for (int i = idx; i < 3 * CH * CH; i += stride) {
            float f = qkv_w[i];
            if (i < CH * CH) f *= QSCALE;
            wq[i] = f2bf(f);
        }
        for (int i = idx; i < CH * CH; i += stride) wp[i] = f2bf(proj_w[i]);
        for (int i = idx; i < 3 * CH; i += stride) {
            float f = qkv_b[i];
            if (i < CH) f *= QSCALE;
            bq[i] = f;
        }
    }
}

// ---------------- QKV GEMM with fused GroupNorm staging (coalesced), 2 o-passes ----
__global__ __launch_bounds__(256) void qkv_gemm(const float* __restrict__ x,
        const float* __restrict__ nw, const float* __restrict__ nb_,
        const float* __restrict__ psum, const float* __restrict__ psq,
        const unsigned short* __restrict__ wq, const float* __restrict__ bq,
        unsigned short* __restrict__ qT, unsigned short* __restrict__ kT,
        unsigned short* __restrict__ vv) {
    int nb = blockIdx.x;       // 0..63 (n tile of 64)
    int og = blockIdx.y;       // 0..5  (o group of 128)
    int b  = blockIdx.z;
    int t = threadIdx.x;
    int wave = t >> 6, lane = t & 63;
    int l15 = lane & 15, quad = lane >> 4;

    __shared__ __align__(16) unsigned short bt[64 * 264];   // 132 dw stride (==4 mod 32)
    __shared__ float wch[CH], bch[CH];

    // phase 1: per-channel affine params (thread t = channel t)
    {
        int c = t;
        int g = c >> 5;
        float S = 0.f, Q = 0.f;
        for (int s = 0; s < 16; ++s) {
            S += psum[(b * NGROUP + g) * 16 + s];
            Q += psq[(b * NGROUP + g) * 16 + s];
        }
        const float M = (float)(CPG * NTOK);
        float mean = S / M;
        float inv  = rsqrtf(Q / M - mean * mean + EPSV);
        float w  = nw[c] * inv;
        wch[c] = w;
        bch[c] = nb_[c] - mean * w;
    }
    __syncthreads();
    // phase 2: coalesced x loads — wave owns one channel per iteration,
    // 64 lanes read 64 consecutive n (256 B per instruction)
    for (int p = 0; p < 64; ++p) {
        int c = p * 4 + wave;
        float w = wch[c], bb = bch[c];
        float v = x[((size_t)(b * CH + c)) * NTOK + nb * 64 + lane];
        bt[lane * 264 + c] = f2bf(v * w + bb);
    }
    __syncthreads();

    for (int pass = 0; pass < 2; ++pass) {
        int o0 = og * 128 + pass * 64 + wave * 16;
        short8 aW[8];
        {
            const unsigned short* wr = wq + (size_t)(o0 + l15) * CH + quad * 8;
            for (int kc = 0; kc < 8; ++kc) aW[kc] = *(const short8*)(wr + kc * 32);
        }
        float4v acc[4];
        for (int nt = 0; nt < 4; ++nt) for (int r = 0; r < 4; ++r) acc[nt][r] = 0.f;
        for (int kc = 0; kc < 8; ++kc) {
            for (int nt = 0; nt < 4; ++nt) {
                short8 pb = *(const short8*)(bt + (nt * 16 + l15) * 264 + kc * 32 + quad * 8);
                acc[nt] = __builtin_amdgcn_mfma_f32_16x16x32_bf16(aW[kc], pb, acc[nt], 0, 0, 0);
            }
        }
        for (int nt = 0; nt < 4; ++nt) {
            int n = nb * 64 + nt * 16 + l15;
            for (int r = 0; r < 4; ++r) {
                int o = o0 + quad * 4 + r;
                float val = acc[nt][r] + bq[o];
                unsigned short bv = f2bf(val);
                int cch = o & 255;
                int seg = o >> 8;          // 0=q (pre-scaled), 1=k, 2=v
                int hh = cch >> 6, ci = cch & 63;
                if (seg == 0)      qT[(((size_t)b * NH + hh) * NTOK + n) * HD + ci] = bv;
                else if (seg == 1) kT[(((size_t)b * NH + hh) * NTOK + n) * HD + ci] = bv;
                else               vv[(((size_t)b * NH + hh) * HD + ci) * NTOK + n] = bv;
            }
        }
    }
}

// ---------------- Flash attention: S^T trick (register P->PV), 128-key tiles, split x4 ----
// (round-7 verified configuration: 128 q/block, 4 blocks/CU)
__global__ __launch_bounds__(256, 4) void attn_kernel(const unsigned short* __restrict__ qT,
        const unsigned short* __restrict__ kT, const unsigned short* __restrict__ vv,
        unsigned short* __restrict__ opb, float* __restrict__ lpb) {
    int nb = blockIdx.x;          // 0..31 : 128 query rows per block
    int h  = blockIdx.y;
    int zb = blockIdx.z;          // (b, split)
    int sp = zb & 3, b = zb >> 2;
    int t = threadIdx.x, wave = t >> 6, lane = t & 63;
    int l15 = lane & 15, quad = lane >> 4;
    int n0 = nb * 128 + wave * 32;     // wave owns 2 m-tiles of 16 rows
    int kv0 = sp * (NTOK / NSPLIT);

    unsigned short* opart = opb + (size_t)sp * ((size_t)BATCH * NTOK * CH);
    float* lpart = lpb + (size_t)sp * (BATCH * NH * NTOK);

    const unsigned short* qbh = qT + ((size_t)(b * NH + h)) * NTOK * HD;
    const unsigned short* kbh = kT + ((size_t)(b * NH + h)) * NTOK * HD;
    const unsigned short* vbh = vv + ((size_t)(b * NH + h)) * HD * NTOK;

    __shared__ __align__(16) unsigned short kbuf[128 * 80];
    __shared__ __align__(16) unsigned short vbuf[64 * 136];

    short8 aQ[2][2];   // B-fragment of QK: B[q-row=l15][hd k=quad*8+j]
    for (int mt = 0; mt < 2; ++mt) {
        aQ[mt][0] = *(const short8*)(qbh + (size_t)(n0 + mt * 16 + l15) * HD + quad * 8);
        aQ[mt][1] = *(const short8*)(qbh + (size_t)(n0 + mt * 16 + l15) * HD + 32 + quad * 8);
    }

    float l_p[2] = {0.f, 0.f};         // per-lane partial denom (q-row = l15)
    float4v o_acc[2][4];
    for (int mt = 0; mt < 2; ++mt)
        for (int ct = 0; ct < 4; ++ct)
            for (int r = 0; r < 4; ++r) o_acc[mt][ct][r] = 0.f;

    for (int ms = kv0; ms < kv0 + NTOK / NSPLIT; ms += 128) {
        __syncthreads();
#pragma unroll
        for (int p = 0; p < 4; ++p) {
            int slot = p * 256 + t;
            int r = slot >> 3, c = slot & 7;
            short8 kd = *(const short8*)(kbh + (size_t)(ms + r) * HD + c * 8);
            *(short8*)(kbuf + r * 80 + c * 8) = kd;
        }
#pragma unroll
        for (int p = 0; p < 4; ++p) {
            int slot = p * 256 + t;
            int r = slot >> 4, c = slot & 15;
            short8 vd = *(const short8*)(vbh + (size_t)r * NTOK + ms + c * 8);
            *(short8*)(vbuf + r * 136 + c * 8) = vd;
        }
        __syncthreads();

#pragma unroll
        for (int kh = 0; kh < 2; ++kh) {      // two 64-key halves
            float4v s[2][4];
#pragma unroll
            for (int nt = 0; nt < 4; ++nt) {
                int krow = kh * 64 + nt * 16 + l15;
                short8 ak0 = *(const short8*)(kbuf + krow * 80 + quad * 8);
                short8 ak1 = *(const short8*)(kbuf + krow * 80 + 32 + quad * 8);
#pragma unroll
                for (int mt = 0; mt < 2; ++mt) {
                    float4v z;
                    for (int r = 0; r < 4; ++r) z[r] = 0.f;
                    z = __builtin_amdgcn_mfma_f32_16x16x32_bf16(ak0, aQ[mt][0], z, 0, 0, 0);
                    z = __builtin_amdgcn_mfma_f32_16x16x32_bf16(ak1, aQ[mt][1], z, 0, 0, 0);
                    s[mt][nt] = z;
                }
            }
            s4bf aP[2][4];
#pragma unroll
            for (int mt = 0; mt < 2; ++mt) {
#pragma unroll
                for (int nt = 0; nt < 4; ++nt) {
                    float e0 = __builtin_amdgcn_exp2f(s[mt][nt][0]);
                    float e1 = __builtin_amdgcn_exp2f(s[mt][nt][1]);
                    float e2 = __builtin_amdgcn_exp2f(s[mt][nt][2]);
                    float e3 = __builtin_amdgcn_exp2f(s[mt][nt][3]);
                    l_p[mt] += (e0 + e1) + (e2 + e3);
                    union { s4bf v; unsigned u[2]; } c;
                    c.u[0] = pk2bf(e0, e1);
                    c.u[1] = pk2bf(e2, e3);
                    aP[mt][nt] = c.v;
                }
            }
#pragma unroll
            for (int ct = 0; ct < 4; ++ct) {
#pragma unroll
                for (int nt = 0; nt < 4; ++nt) {
                    s4bf bv = *(const s4bf*)(vbuf + (ct * 16 + l15) * 136 + kh * 64 + nt * 16 + quad * 4);
#pragma unroll
                    for (int mt = 0; mt < 2; ++mt)
                        o_acc[mt][ct] = __builtin_amdgcn_mfma_f32_16x16x16bf16_1k(aP[mt][nt], bv, o_acc[mt][ct], 0, 0, 0);
                }
            }
        }
    }
    // reduce denom over the 4 quads (key blocks); q-row = l15
    for (int mt = 0; mt < 2; ++mt) {
        l_p[mt] += __shfl_xor(l_p[mt], 16, 64);
        l_p[mt] += __shfl_xor(l_p[mt], 32, 64);
    }
    // store unnormalized partial O (bf16): C-layout col=l15=d, row=quad*4+r=q-row
    for (int mt = 0; mt < 2; ++mt) {
        for (int ct = 0; ct < 4; ++ct) {
            for (int r = 0; r < 4; ++r) {
                int n = n0 + mt * 16 + quad * 4 + r;
                int cg = h * HD + ct * 16 + l15;
                opart[((size_t)b * NTOK + n) * CH + cg] = f2bf(o_acc[mt][ct][r]);
            }
        }
        if (lane < 16)
            lpart[((size_t)(b * NH + h)) * NTOK + n0 + mt * 16 + lane] = l_p[mt];
    }
}

// ---------------- Proj GEMM with fused split-combine + bias + residual (R7 config) ----
__global__ __launch_bounds__(256) void proj_gemm(const unsigned short* __restrict__ opb,
        const float* __restrict__ lpb, const unsigned short* __restrict__ wp,
        const float* __restrict__ proj_b, const float* __restrict__ x,
        float* __restrict__ out) {
    int nb = blockIdx.x;   // 0..63
    int cb = blockIdx.y;   // 0..3
    int b  = blockIdx.z;
    int t = threadIdx.x, wave = t >> 6, lane = t & 63;
    int l15 = lane & 15, quad = lane >> 4;
    int c0 = cb * 64 + wave * 16;
    const size_t OP = (size_t)BATCH * NTOK * CH;
    const size_t LP = (size_t)BATCH * NH * NTOK;

    __shared__ __align__(16) unsigned short bt[64 * 264];
    __shared__ float rl[64 * 4];

    short8 aW[8];
    {
        const unsigned short* wr = wp + (size_t)(c0 + l15) * CH + quad * 8;
        for (int kc = 0; kc < 8; ++kc) aW[kc] = *(const short8*)(wr + kc * 32);
    }
    // per-row, per-head reciprocal denominators (normalization must precede channel-sum)
    {
        int r = t >> 2, h = t & 3;
        size_t lidx = ((size_t)(b * NH + h)) * NTOK + nb * 64 + r;
        float ls = (lpb[lidx] + lpb[LP + lidx]) + (lpb[2 * LP + lidx] + lpb[3 * LP + lidx]);
        rl[r * 4 + h] = 1.0f / ls;
    }
    __syncthreads();
    // stage normalized O tile from the 4 split partials
    for (int p = 0; p < 8; ++p) {
        int slot = p * 256 + t;
        int r = slot >> 5, c = slot & 31;
        size_t base = ((size_t)b * NTOK + nb * 64 + r) * CH + c * 8;
        short8 o0 = *(const short8*)(opb + base);
        short8 o1 = *(const short8*)(opb + OP + base);
        short8 o2 = *(const short8*)(opb + 2 * OP + base);
        short8 o3 = *(const short8*)(opb + 3 * OP + base);
        float rinv = rl[r * 4 + (c >> 3)];
        short8 m;
        for (int j = 0; j < 8; ++j) {
            float f = (bf2f((unsigned short)o0[j]) + bf2f((unsigned short)o1[j]))
                    + (bf2f((unsigned short)o2[j]) + bf2f((unsigned short)o3[j]));
            m[j] = (short)f2bf(f * rinv);
        }
        *(short8*)(bt + r * 264 + c * 8) = m;
    }
    __syncthreads();

    float4v acc[4];
    for (int nt = 0; nt < 4; ++nt) for (int r = 0; r < 4; ++r) acc[nt][r] = 0.f;
    for (int kc = 0; kc < 8; ++kc) {
        for (int nt = 0; nt < 4; ++nt) {
            short8 pb = *(const short8*)(bt + (nt * 16 + l15) * 264 + kc * 32 + quad * 8);
            acc[nt] = __builtin_amdgcn_mfma_f32_16x16x32_bf16(aW[kc], pb, acc[nt], 0, 0, 0);
        }
    }
    for (int nt = 0; nt < 4; ++nt) {
        int n = nb * 64 + nt * 16 + l15;
        for (int r = 0; r < 4; ++r) {
            int cc = c0 + quad * 4 + r;
            size_t idx = ((size_t)(b * CH + cc)) * NTOK + n;
            out[idx] = acc[nt][r] + proj_b[cc] + x[idx];
        }
    }
}

extern "C" void kernel_launch(void* const* d_in, const int* in_sizes, int n_in,
                              void* d_out, int out_size, void* d_ws, size_t ws_size,
                              hipStream_t stream) {
    const float* x      = (const float*)d_in[0];
    const float* norm_w = (const float*)d_in[1];
    const float* norm_b = (const float*)d_in[2];
    const float* qkv_w  = (const float*)d_in[3];
    const float* qkv_b  = (const float*)d_in[4];
    const float* proj_w = (const float*)d_in[5];
    const float* proj_b = (const float*)d_in[6];
    float* out = (float*)d_out;

    char* ws = (char*)d_ws;
    float* psum  = (float*)ws;                       // 256 f
    float* psq   = (float*)(ws + 1024);              // 256 f
    float* bqs   = (float*)(ws + 4096);              // 768 f
    unsigned short* wqb = (unsigned short*)(ws + 8192);        // 3*256*256 bf16 -> 401408
    unsigned short* wpb = (unsigned short*)(ws + 401408);      // 256*256 bf16   -> 532480
    float* lpb = (float*)(ws + 532480);              // 4 * 2*4*4096 f = 512 KB
    const size_t MB4 = 4194304;
    unsigned short* opb = (unsigned short*)(ws + 2097152);     // 4 x 4 MB partials
    unsigned short* qT = (unsigned short*)(ws + 2097152 + 4 * MB4);
    unsigned short* kT = (unsigned short*)(ws + 2097152 + 5 * MB4);
    unsigned short* vv = (unsigned short*)(ws + 2097152 + 6 * MB4);

    prep<<<dim3(512), dim3(256), 0, stream>>>(x, qkv_w, qkv_b, proj_w, psum, psq, wqb, bqs, wpb);
    qkv_gemm<<<dim3(64, 6, BATCH), dim3(256), 0, stream>>>(x, norm_w, norm_b, psum, psq, wqb, bqs, qT, kT, vv);
    attn_kernel<<<dim3(32, NH, BATCH * NSPLIT), dim3(256), 0, stream>>>(qT, kT, vv, opb, lpb);
    proj_gemm<<<dim3(64, 4, BATCH), dim3(256), 0, stream>>>(opb, lpb, wpb, proj_b, x, out);
}